// Round 5
// baseline (177.941 us; speedup 1.0000x reference)
//
#include <hip/hip_runtime.h>
#include <math.h>

#define NB 8
#define MSEG 16
#define PPIX (640*640)
#define PV4 (PPIX/4)          // 102400 float4/int4 groups per batch
#define GRIDX 400             // 400 blocks * 256 threads = 102400 groups, 1 group/thread
#define DELTA_AGG 0.5f
#define DELTA_DIS 3.0f

// ws float layout — every slot written unconditionally each call, no zero-init.
// val index v: 0..63 = kern-sums (v = ch*16+m), 64..79 = cnt_k, 80..95 = cnt_t
#define OFF_P1 0                               // [NB][GRIDX][96] per-block partials
#define OFF_GC (NB*GRIDX*96)                   // [NB][96]: 0..63 G (m*4+ch), 64..79 cnt_k, 80..95 cnt_t
#define OFF_P2 (OFF_GC + NB*96)                // [NB][GRIDX][16] per-block agg partials

// ---------------- pass 1: register-binned segment sums by kern ----------------
__global__ __launch_bounds__(256) void pass1_kernel(
    const float* __restrict__ preds, const int* __restrict__ targets,
    float* __restrict__ ws) {
  const int n = blockIdx.y, blk = blockIdx.x;
  const int tid = threadIdx.x, lane = tid & 63, w = tid >> 6;

  const float4* __restrict__ c0 = (const float4*)(preds + ((size_t)n*6 + 2)*PPIX);
  const float4* __restrict__ c1 = (const float4*)(preds + ((size_t)n*6 + 3)*PPIX);
  const float4* __restrict__ c2 = (const float4*)(preds + ((size_t)n*6 + 4)*PPIX);
  const float4* __restrict__ c3 = (const float4*)(preds + ((size_t)n*6 + 5)*PPIX);
  const int4*  __restrict__ textv = (const int4*)(targets + (size_t)n*2*PPIX);
  const int4*  __restrict__ kernv = (const int4*)(targets + ((size_t)n*2 + 1)*PPIX);

  const int g = blk*256 + tid;
  const int4 kk = kernv[g];
  const int4 tt = textv[g];
  const float4 a = c0[g], b = c1[g], c = c2[g], d = c3[g];

  float acc[64];            // acc[ch*16+m], static indexing only
  float ck[MSEG];
  int   ct[MSEG];
#pragma unroll
  for (int v = 0; v < 64; ++v) acc[v] = 0.f;
#pragma unroll
  for (int m = 0; m < MSEG; ++m) { ck[m] = 0.f; ct[m] = 0; }

#define PIX1(K, T, A0, A1, A2, A3) do {                 \
    int k_ = (K), t_ = (T);                             \
    _Pragma("unroll")                                   \
    for (int m = 0; m < MSEG; ++m) {                    \
      float fk = (k_ == m) ? 1.0f : 0.0f;               \
      acc[0*16+m] = fmaf(fk, (A0), acc[0*16+m]);        \
      acc[1*16+m] = fmaf(fk, (A1), acc[1*16+m]);        \
      acc[2*16+m] = fmaf(fk, (A2), acc[2*16+m]);        \
      acc[3*16+m] = fmaf(fk, (A3), acc[3*16+m]);        \
      ck[m] += fk;                                      \
      ct[m] += (t_ == m);                               \
    } } while (0)

  PIX1(kk.x, tt.x, a.x, b.x, c.x, d.x);
  PIX1(kk.y, tt.y, a.y, b.y, c.y, d.y);
  PIX1(kk.z, tt.z, a.z, b.z, c.z, d.z);
  PIX1(kk.w, tt.w, a.w, b.w, c.w, d.w);
#undef PIX1

  // 64-value xor reduce-scatter: lane l ends holding the 64-lane sum of acc[l]
#pragma unroll
  for (int s = 0; s < 6; ++s) {
    const int dist = 32 >> s;
    const bool hi = (lane & dist) != 0;
#pragma unroll
    for (int v = 0; v < (32 >> s); ++v) {
      float keep = hi ? acc[v + (32 >> s)] : acc[v];
      float send = hi ? acc[v] : acc[v + (32 >> s)];
      acc[v] = keep + __shfl_xor(send, dist);
    }
  }

  // 32-value (ck, ct) reduce-scatter: lane l ends holding cnt-val (l>>1)
  float cnts[32];
#pragma unroll
  for (int m = 0; m < MSEG; ++m) { cnts[m] = ck[m]; cnts[16+m] = (float)ct[m]; }
#pragma unroll
  for (int s = 0; s < 5; ++s) {
    const int dist = 32 >> s;        // 32,16,8,4,2
    const int half = 16 >> s;        // 16,8,4,2,1
    const bool hi = (lane & dist) != 0;
#pragma unroll
    for (int v = 0; v < half; ++v) {
      float keep = hi ? cnts[v + half] : cnts[v];
      float send = hi ? cnts[v] : cnts[v + half];
      cnts[v] = keep + __shfl_xor(send, dist);
    }
  }
  cnts[0] += __shfl_xor(cnts[0], 1);

  __shared__ float s_vals[4][64];
  __shared__ float s_cnt[4][32];
  s_vals[w][lane] = acc[0];
  if (!(lane & 1)) s_cnt[w][lane >> 1] = cnts[0];
  __syncthreads();

  float* part = ws + OFF_P1 + ((size_t)n*GRIDX + blk)*96;
  if (tid < 64) {
    part[tid] = s_vals[0][tid] + s_vals[1][tid] + s_vals[2][tid] + s_vals[3][tid];
  } else if (tid < 96) {
    int i = tid - 64;
    part[tid] = s_cnt[0][i] + s_cnt[1][i] + s_cnt[2][i] + s_cnt[3][i];
  }
}

// ------------- finalize G + discrimination loss (one block/batch) -------------
__global__ __launch_bounds__(256) void finalize_dis_kernel(
    float* __restrict__ ws, float* __restrict__ out) {
  const int n = blockIdx.x;
  const int tid = threadIdx.x;

  __shared__ float s_raw[96];
  __shared__ float s_G[MSEG][4];
  __shared__ int   s_valid[MSEG];
  __shared__ int   s_nv;
  __shared__ float red[256];

  if (tid < 96) {
    const float* p = ws + OFF_P1 + (size_t)n*GRIDX*96 + tid;
    float s = 0.f;
#pragma unroll 4
    for (int b = 0; b < GRIDX; ++b) s += p[(size_t)b*96];
    s_raw[tid] = s;
  }
  __syncthreads();

  if (tid < 64) {
    int ch = tid >> 4, m = tid & 15;
    float gv = s_raw[tid] / fmaxf(s_raw[64 + m], 1.0f);
    s_G[m][ch] = gv;
    ws[OFF_GC + n*96 + m*4 + ch] = gv;     // G in m*4+ch order for pass2 float4 read
  } else if (tid < 96) {
    ws[OFF_GC + n*96 + tid] = s_raw[tid];  // cnt_k at 64.., cnt_t at 80..
  }
  if (tid < MSEG)
    s_valid[tid] = (tid >= 1) && (s_raw[64 + tid] > 0.f) && (s_raw[80 + tid] > 0.f);
  __syncthreads();
  if (tid == 0) { int nv = 0; for (int m = 0; m < MSEG; m++) nv += s_valid[m]; s_nv = nv; }

  float lp = 0.f;
  {
    int i = tid >> 4, j = tid & 15;
    if (i != j && s_valid[i] && s_valid[j]) {
      float dx = s_G[i][0] - s_G[j][0];
      float dy = s_G[i][1] - s_G[j][1];
      float dz = s_G[i][2] - s_G[j][2];
      float dw = s_G[i][3] - s_G[j][3];
      float dist = sqrtf(dx*dx + dy*dy + dz*dz + dw*dw);
      float t = fmaxf(DELTA_DIS - dist, 0.f);
      lp = logf(t*t + 1.f);
    }
  }
  red[tid] = lp;
  __syncthreads();
  for (int s = 128; s > 0; s >>= 1) {
    if (tid < s) red[tid] += red[tid + s];
    __syncthreads();
  }
  if (tid == 0) {
    int nv = s_nv;
    float dis = 0.f;
    if (nv > 1) dis = 0.5f * red[0] / (float)(nv * (nv - 1));
    out[NB + n] = dis;
  }
}

// ---------------- pass 2: aggregation loss, register-binned by text ----------------
__global__ __launch_bounds__(256) void pass2_kernel(
    const float* __restrict__ preds, const int* __restrict__ targets,
    float* __restrict__ ws) {
  const int n = blockIdx.y, blk = blockIdx.x;
  const int tid = threadIdx.x, lane = tid & 63, w = tid >> 6;

  const float4* __restrict__ c0 = (const float4*)(preds + ((size_t)n*6 + 2)*PPIX);
  const float4* __restrict__ c1 = (const float4*)(preds + ((size_t)n*6 + 3)*PPIX);
  const float4* __restrict__ c2 = (const float4*)(preds + ((size_t)n*6 + 4)*PPIX);
  const float4* __restrict__ c3 = (const float4*)(preds + ((size_t)n*6 + 5)*PPIX);
  const int4*  __restrict__ textv = (const int4*)(targets + (size_t)n*2*PPIX);

  __shared__ float4 s_G[MSEG];
  if (tid < MSEG) s_G[tid] = ((const float4*)(ws + OFF_GC + n*96))[tid];
  __syncthreads();

  const int g = blk*256 + tid;
  const int4 tt = textv[g];
  const float4 a = c0[g], b = c1[g], c = c2[g], d = c3[g];

  float ls[MSEG];
#pragma unroll
  for (int m = 0; m < MSEG; ++m) ls[m] = 0.f;

#define PIX2(T, A0, A1, A2, A3) do {                            \
    int t_ = (T);                                               \
    float4 gv = s_G[t_];                                        \
    float dx = (A0) - gv.x, dy = (A1) - gv.y;                   \
    float dz = (A2) - gv.z, dw = (A3) - gv.w;                   \
    float sq = fmaf(dx, dx, fmaf(dy, dy, fmaf(dz, dz, dw*dw))); \
    float dd = fmaxf(__fsqrt_rn(sq) - DELTA_AGG, 0.f);          \
    float l = __logf(fmaf(dd, dd, 1.f));                        \
    _Pragma("unroll")                                           \
    for (int m = 0; m < MSEG; ++m)                              \
      ls[m] += (t_ == m) ? l : 0.f;                             \
  } while (0)

  PIX2(tt.x, a.x, b.x, c.x, d.x);
  PIX2(tt.y, a.y, b.y, c.y, d.y);
  PIX2(tt.z, a.z, b.z, c.z, d.z);
  PIX2(tt.w, a.w, b.w, c.w, d.w);
#undef PIX2

  // 16-value reduce-scatter (dist 32,16,8,4) + 2-stage finish: lane l holds val (l>>2)
#pragma unroll
  for (int s = 0; s < 4; ++s) {
    const int dist = 32 >> s;
    const bool hi = (lane & dist) != 0;
#pragma unroll
    for (int v = 0; v < (8 >> s); ++v) {
      float keep = hi ? ls[v + (8 >> s)] : ls[v];
      float send = hi ? ls[v] : ls[v + (8 >> s)];
      ls[v] = keep + __shfl_xor(send, dist);
    }
  }
  float t = ls[0];
  t += __shfl_xor(t, 2);
  t += __shfl_xor(t, 1);

  __shared__ float s_red[4][MSEG];
  if ((lane & 3) == 0) s_red[w][lane >> 2] = t;
  __syncthreads();
  if (tid < MSEG)
    ws[OFF_P2 + ((size_t)n*GRIDX + blk)*16 + tid] =
        s_red[0][tid] + s_red[1][tid] + s_red[2][tid] + s_red[3][tid];
}

// ---------------- finalize aggregation loss (one wave/batch) ----------------
__global__ __launch_bounds__(64) void finalize_agg_kernel(
    const float* __restrict__ ws, float* __restrict__ out) {
  const int n = blockIdx.x;
  const int tid = threadIdx.x;

  float lm = 0.f, vc = 0.f;
  if (tid >= 1 && tid < MSEG) {
    const float* p = ws + OFF_P2 + (size_t)n*GRIDX*16 + tid;
    float s = 0.f;
#pragma unroll 4
    for (int b = 0; b < GRIDX; ++b) s += p[(size_t)b*16];
    float ckv = ws[OFF_GC + n*96 + 64 + tid];
    float ctv = ws[OFF_GC + n*96 + 80 + tid];
    if (ckv > 0.f && ctv > 0.f) {
      vc = 1.f;
      lm = s / fmaxf(ctv, 1.f);
    }
  }
#pragma unroll
  for (int off = 32; off > 0; off >>= 1) {
    lm += __shfl_down(lm, off);
    vc += __shfl_down(vc, off);
  }
  if (tid == 0) {
    int nv = (int)(vc + 0.5f);
    out[n] = lm / (float)(nv > 1 ? nv : 1);
  }
}

extern "C" void kernel_launch(void* const* d_in, const int* in_sizes, int n_in,
                              void* d_out, int out_size, void* d_ws, size_t ws_size,
                              hipStream_t stream) {
  const float* preds   = (const float*)d_in[0];
  const int*   targets = (const int*)d_in[1];
  float* out = (float*)d_out;
  float* ws  = (float*)d_ws;

  dim3 grid(GRIDX, NB);
  pass1_kernel<<<grid, 256, 0, stream>>>(preds, targets, ws);
  finalize_dis_kernel<<<NB, 256, 0, stream>>>(ws, out);
  pass2_kernel<<<grid, 256, 0, stream>>>(preds, targets, ws);
  finalize_agg_kernel<<<NB, 64, 0, stream>>>(ws, out);
}

// Round 6
// 73.996 us; speedup vs baseline: 2.4047x; 2.4047x over previous
//
#include <hip/hip_runtime.h>
#include <math.h>

#define NB 8
#define MSEG 16
#define PPIX (640*640)
#define PV4 (PPIX/4)          // 102400 float4/int4 groups per batch
#define GRIDX 100             // 100 blocks * 256 thr * 4 iters = 102400 groups
#define STRIDE (GRIDX*256)    // 25600
#define DELTA_AGG 0.5f
#define DELTA_DIS 3.0f

// ws float layout — every slot written unconditionally, no zero-init needed.
#define OFF_P1 0                               // [NB][GRIDX][80]: 0..63 sums (ch*16+m), 64..79 cnt_k
#define OFF_GC (NB*GRIDX*80)                   // [NB][80]: 0..63 G (m*4+ch), 64..79 cnt_k
#define OFF_P2 (OFF_GC + NB*80)                // [NB][GRIDX][32]: 0..15 lsum, 16..31 cnt_t

// ---------------- pass 1: register-binned segment sums by kern ----------------
__global__ __launch_bounds__(256, 4) void pass1_kernel(
    const float* __restrict__ preds, const int* __restrict__ targets,
    float* __restrict__ ws) {
  const int n = blockIdx.y, blk = blockIdx.x;
  const int tid = threadIdx.x, lane = tid & 63, w = tid >> 6;

  const float4* __restrict__ c0 = (const float4*)(preds + ((size_t)n*6 + 2)*PPIX);
  const float4* __restrict__ c1 = (const float4*)(preds + ((size_t)n*6 + 3)*PPIX);
  const float4* __restrict__ c2 = (const float4*)(preds + ((size_t)n*6 + 4)*PPIX);
  const float4* __restrict__ c3 = (const float4*)(preds + ((size_t)n*6 + 5)*PPIX);
  const int4*  __restrict__ kernv = (const int4*)(targets + ((size_t)n*2 + 1)*PPIX);

  // acc[ch*16+m] for ch 0..3; acc[64+m] = cnt_k. Static indexing only.
  float acc[80];
#pragma unroll
  for (int v = 0; v < 80; ++v) acc[v] = 0.f;

#define PIX1(K, A0, A1, A2, A3) do {                    \
    int k_ = (K);                                       \
    _Pragma("unroll")                                   \
    for (int m = 0; m < MSEG; ++m) {                    \
      float fk = (k_ == m) ? 1.0f : 0.0f;               \
      acc[m]      = fmaf(fk, (A0), acc[m]);             \
      acc[16+m]   = fmaf(fk, (A1), acc[16+m]);          \
      acc[32+m]   = fmaf(fk, (A2), acc[32+m]);          \
      acc[48+m]   = fmaf(fk, (A3), acc[48+m]);          \
      acc[64+m]  += fk;                                 \
    } } while (0)

  const int base = blk*256 + tid;
  // software pipeline: prefetch iter it+1 before computing iter it
  int4 kk = kernv[base];
  float4 a = c0[base], b = c1[base], c = c2[base], d = c3[base];
#pragma unroll
  for (int it = 0; it < 4; ++it) {
    int4 kk_n; float4 an, bn, cn, dn;
    if (it < 3) {
      const int p = base + (it+1)*STRIDE;
      kk_n = kernv[p]; an = c0[p]; bn = c1[p]; cn = c2[p]; dn = c3[p];
    }
    PIX1(kk.x, a.x, b.x, c.x, d.x);
    PIX1(kk.y, a.y, b.y, c.y, d.y);
    PIX1(kk.z, a.z, b.z, c.z, d.z);
    PIX1(kk.w, a.w, b.w, c.w, d.w);
    if (it < 3) { kk = kk_n; a = an; b = bn; c = cn; d = dn; }
  }
#undef PIX1

  // 64-value xor reduce-scatter: lane l ends holding the 64-lane sum of acc[l]
#pragma unroll
  for (int s = 0; s < 6; ++s) {
    const int dist = 32 >> s;
    const bool hi = (lane & dist) != 0;
#pragma unroll
    for (int v = 0; v < (32 >> s); ++v) {
      float keep = hi ? acc[v + (32 >> s)] : acc[v];
      float send = hi ? acc[v] : acc[v + (32 >> s)];
      acc[v] = keep + __shfl_xor(send, dist);
    }
  }
  // 16-value reduce-scatter on cnt_k: 4-lane group g ends holding cnt_k[g]
  float cn16[16];
#pragma unroll
  for (int m = 0; m < MSEG; ++m) cn16[m] = acc[64+m];
#pragma unroll
  for (int s = 0; s < 4; ++s) {
    const int dist = 32 >> s;        // 32,16,8,4
    const int half = 8 >> s;         // 8,4,2,1
    const bool hi = (lane & dist) != 0;
#pragma unroll
    for (int v = 0; v < half; ++v) {
      float keep = hi ? cn16[v + half] : cn16[v];
      float send = hi ? cn16[v] : cn16[v + half];
      cn16[v] = keep + __shfl_xor(send, dist);
    }
  }
  float ckt = cn16[0];
  ckt += __shfl_xor(ckt, 2);
  ckt += __shfl_xor(ckt, 1);

  __shared__ float s_v[4][64];
  __shared__ float s_c[4][16];
  s_v[w][lane] = acc[0];
  if ((lane & 3) == 0) s_c[w][lane >> 2] = ckt;
  __syncthreads();

  float* part = ws + OFF_P1 + ((size_t)n*GRIDX + blk)*80;
  if (tid < 64) {
    part[tid] = s_v[0][tid] + s_v[1][tid] + s_v[2][tid] + s_v[3][tid];
  } else if (tid < 80) {
    int i = tid - 64;
    part[tid] = s_c[0][i] + s_c[1][i] + s_c[2][i] + s_c[3][i];
  }
}

// ------------- finalize G (one block/batch) -------------
__global__ __launch_bounds__(128) void finalize_G_kernel(float* __restrict__ ws) {
  const int n = blockIdx.x;
  const int tid = threadIdx.x;
  __shared__ float raw[80];
  if (tid < 80) {
    const float* p = ws + OFF_P1 + (size_t)n*GRIDX*80 + tid;
    float s = 0.f;
#pragma unroll 4
    for (int b = 0; b < GRIDX; ++b) s += p[(size_t)b*80];
    raw[tid] = s;
  }
  __syncthreads();
  if (tid < 64) {
    int ch = tid >> 4, m = tid & 15;
    ws[OFF_GC + n*80 + m*4 + ch] = raw[tid] / fmaxf(raw[64 + m], 1.0f);
  } else if (tid < 80) {
    ws[OFF_GC + n*80 + tid] = raw[tid];   // cnt_k
  }
}

// ---------------- pass 2: agg-loss sums + cnt_t by text ----------------
__global__ __launch_bounds__(256, 4) void pass2_kernel(
    const float* __restrict__ preds, const int* __restrict__ targets,
    float* __restrict__ ws) {
  const int n = blockIdx.y, blk = blockIdx.x;
  const int tid = threadIdx.x, lane = tid & 63, w = tid >> 6;

  const float4* __restrict__ c0 = (const float4*)(preds + ((size_t)n*6 + 2)*PPIX);
  const float4* __restrict__ c1 = (const float4*)(preds + ((size_t)n*6 + 3)*PPIX);
  const float4* __restrict__ c2 = (const float4*)(preds + ((size_t)n*6 + 4)*PPIX);
  const float4* __restrict__ c3 = (const float4*)(preds + ((size_t)n*6 + 5)*PPIX);
  const int4*  __restrict__ textv = (const int4*)(targets + (size_t)n*2*PPIX);

  __shared__ float4 s_G[MSEG];
  if (tid < MSEG) s_G[tid] = ((const float4*)(ws + OFF_GC + n*80))[tid];
  __syncthreads();

  float ls[MSEG], ct[MSEG];
#pragma unroll
  for (int m = 0; m < MSEG; ++m) { ls[m] = 0.f; ct[m] = 0.f; }

#define PIX2(T, A0, A1, A2, A3) do {                            \
    int t_ = (T);                                               \
    float4 gv = s_G[t_];                                        \
    float dx = (A0) - gv.x, dy = (A1) - gv.y;                   \
    float dz = (A2) - gv.z, dw = (A3) - gv.w;                   \
    float sq = fmaf(dx, dx, fmaf(dy, dy, fmaf(dz, dz, dw*dw))); \
    float dd = fmaxf(__fsqrt_rn(sq) - DELTA_AGG, 0.f);          \
    float l = __logf(fmaf(dd, dd, 1.f));                        \
    _Pragma("unroll")                                           \
    for (int m = 0; m < MSEG; ++m) {                            \
      float fk = (t_ == m) ? 1.0f : 0.0f;                       \
      ls[m] = fmaf(fk, l, ls[m]);                               \
      ct[m] += fk;                                              \
    } } while (0)

  const int base = blk*256 + tid;
  int4 tt = textv[base];
  float4 a = c0[base], b = c1[base], c = c2[base], d = c3[base];
#pragma unroll
  for (int it = 0; it < 4; ++it) {
    int4 tt_n; float4 an, bn, cn, dn;
    if (it < 3) {
      const int p = base + (it+1)*STRIDE;
      tt_n = textv[p]; an = c0[p]; bn = c1[p]; cn = c2[p]; dn = c3[p];
    }
    PIX2(tt.x, a.x, b.x, c.x, d.x);
    PIX2(tt.y, a.y, b.y, c.y, d.y);
    PIX2(tt.z, a.z, b.z, c.z, d.z);
    PIX2(tt.w, a.w, b.w, c.w, d.w);
    if (it < 3) { tt = tt_n; a = an; b = bn; c = cn; d = dn; }
  }
#undef PIX2

  // two 16-value reduce-scatters: 4-lane group g ends holding value g
  float t0, t1;
  {
#pragma unroll
    for (int s = 0; s < 4; ++s) {
      const int dist = 32 >> s; const int half = 8 >> s;
      const bool hi = (lane & dist) != 0;
#pragma unroll
      for (int v = 0; v < half; ++v) {
        float keep = hi ? ls[v + half] : ls[v];
        float send = hi ? ls[v] : ls[v + half];
        ls[v] = keep + __shfl_xor(send, dist);
      }
    }
    t0 = ls[0]; t0 += __shfl_xor(t0, 2); t0 += __shfl_xor(t0, 1);
#pragma unroll
    for (int s = 0; s < 4; ++s) {
      const int dist = 32 >> s; const int half = 8 >> s;
      const bool hi = (lane & dist) != 0;
#pragma unroll
      for (int v = 0; v < half; ++v) {
        float keep = hi ? ct[v + half] : ct[v];
        float send = hi ? ct[v] : ct[v + half];
        ct[v] = keep + __shfl_xor(send, dist);
      }
    }
    t1 = ct[0]; t1 += __shfl_xor(t1, 2); t1 += __shfl_xor(t1, 1);
  }

  __shared__ float s_l[4][16];
  __shared__ float s_t[4][16];
  if ((lane & 3) == 0) { s_l[w][lane >> 2] = t0; s_t[w][lane >> 2] = t1; }
  __syncthreads();

  float* part = ws + OFF_P2 + ((size_t)n*GRIDX + blk)*32;
  if (tid < 16)
    part[tid] = s_l[0][tid] + s_l[1][tid] + s_l[2][tid] + s_l[3][tid];
  else if (tid < 32) {
    int i = tid - 16;
    part[tid] = s_t[0][i] + s_t[1][i] + s_t[2][i] + s_t[3][i];
  }
}

// ------------- finalize: agg + dis (one block/batch) -------------
__global__ __launch_bounds__(256) void finalize2_kernel(
    const float* __restrict__ ws, float* __restrict__ out) {
  const int n = blockIdx.x;
  const int tid = threadIdx.x;

  __shared__ float s2[32];        // 0..15 lsum, 16..31 cnt_t
  __shared__ float sG[MSEG][4];
  __shared__ float sck[MSEG];
  __shared__ int   sval[MSEG];
  __shared__ int   snv;
  __shared__ float red[256];
  __shared__ float agg_sum;

  if (tid < 32) {
    const float* p = ws + OFF_P2 + (size_t)n*GRIDX*32 + tid;
    float s = 0.f;
#pragma unroll 4
    for (int b = 0; b < GRIDX; ++b) s += p[(size_t)b*32];
    s2[tid] = s;
  } else if (tid >= 32 && tid < 48) {
    sck[tid - 32] = ws[OFF_GC + n*80 + 64 + (tid - 32)];
  } else if (tid >= 64 && tid < 128) {
    int i = tid - 64;
    sG[i >> 2][i & 3] = ws[OFF_GC + n*80 + i];
  }
  __syncthreads();
  if (tid < MSEG)
    sval[tid] = (tid >= 1) && (sck[tid] > 0.f) && (s2[16 + tid] > 0.f);
  __syncthreads();
  if (tid == 0) { int nv = 0; for (int m = 0; m < MSEG; m++) nv += sval[m]; snv = nv; }

  // agg reduction
  float av = 0.f;
  if (tid < MSEG && sval[tid]) av = s2[tid] / fmaxf(s2[16 + tid], 1.0f);
  red[tid] = av;
  __syncthreads();
  for (int s = 128; s > 0; s >>= 1) {
    if (tid < s) red[tid] += red[tid + s];
    __syncthreads();
  }
  if (tid == 0) agg_sum = red[0];
  __syncthreads();

  // dis pairwise
  float lp = 0.f;
  {
    int i = tid >> 4, j = tid & 15;
    if (i != j && sval[i] && sval[j]) {
      float dx = sG[i][0] - sG[j][0];
      float dy = sG[i][1] - sG[j][1];
      float dz = sG[i][2] - sG[j][2];
      float dw = sG[i][3] - sG[j][3];
      float dist = sqrtf(dx*dx + dy*dy + dz*dz + dw*dw);
      float t = fmaxf(DELTA_DIS - dist, 0.f);
      lp = logf(t*t + 1.f);
    }
  }
  red[tid] = lp;
  __syncthreads();
  for (int s = 128; s > 0; s >>= 1) {
    if (tid < s) red[tid] += red[tid + s];
    __syncthreads();
  }
  if (tid == 0) {
    int nv = snv;
    out[n] = agg_sum / (float)(nv > 1 ? nv : 1);
    out[NB + n] = (nv > 1) ? 0.5f * red[0] / (float)(nv * (nv - 1)) : 0.f;
  }
}

extern "C" void kernel_launch(void* const* d_in, const int* in_sizes, int n_in,
                              void* d_out, int out_size, void* d_ws, size_t ws_size,
                              hipStream_t stream) {
  const float* preds   = (const float*)d_in[0];
  const int*   targets = (const int*)d_in[1];
  float* out = (float*)d_out;
  float* ws  = (float*)d_ws;

  dim3 grid(GRIDX, NB);
  pass1_kernel<<<grid, 256, 0, stream>>>(preds, targets, ws);
  finalize_G_kernel<<<NB, 128, 0, stream>>>(ws);
  pass2_kernel<<<grid, 256, 0, stream>>>(preds, targets, ws);
  finalize2_kernel<<<NB, 256, 0, stream>>>(ws, out);
}

// Round 7
// 58.792 us; speedup vs baseline: 3.0266x; 1.2586x over previous
//
#include <hip/hip_runtime.h>
#include <math.h>

#define NB 8
#define MSEG 16
#define PPIX (640*640)
#define PV4 (PPIX/4)          // 102400 float4/int4 groups per batch
#define GRIDX 128             // 1024 blocks total = 4/CU exact
#define STRIDE (GRIDX*256)    // 32768; 3 full iters = 98304, remainder 4096
#define FULLCOV (3*STRIDE)    // 98304
#define DELTA_AGG 0.5f
#define DELTA_DIS 3.0f

typedef float v2f __attribute__((ext_vector_type(2)));

// ws float layout (atomic accumulators zeroed by in-graph memset)
#define OFF_A1 0              // [NB][80]: 0..63 kern-sums (ch*16+m), 64..79 cnt_k
#define OFF_GC (NB*80)        // [NB][80]: 0..63 G (m*4+ch), 64..79 cnt_k copy
#define OFF_A2 (NB*160)       // [NB][32]: 0..15 lsum, 16..31 cnt_t
#define WS_ZERO_FLOATS (NB*192)

// ---------------- pass 1: register-binned segment sums by kern ----------------
__global__ __launch_bounds__(256, 3) void pass1_kernel(
    const float* __restrict__ preds, const int* __restrict__ targets,
    float* __restrict__ ws) {
  const int n = blockIdx.y, blk = blockIdx.x;
  const int tid = threadIdx.x, lane = tid & 63, w = tid >> 6;

  const float4* __restrict__ pc0 = (const float4*)(preds + ((size_t)n*6 + 2)*PPIX);
  const float4* __restrict__ pc1 = (const float4*)(preds + ((size_t)n*6 + 3)*PPIX);
  const float4* __restrict__ pc2 = (const float4*)(preds + ((size_t)n*6 + 4)*PPIX);
  const float4* __restrict__ pc3 = (const float4*)(preds + ((size_t)n*6 + 5)*PPIX);
  const int4*  __restrict__ kernv = (const int4*)(targets + ((size_t)n*2 + 1)*PPIX);

  // packed accumulators: acc01[m]=(ch0,ch1), acc23[m]=(ch2,ch3), cntk[m]
  v2f acc01[MSEG], acc23[MSEG];
  float cntk[MSEG];
#pragma unroll
  for (int m = 0; m < MSEG; ++m) {
    acc01[m] = (v2f){0.f, 0.f}; acc23[m] = (v2f){0.f, 0.f}; cntk[m] = 0.f;
  }

#define PIX1(K, A0, A1, A2, A3) do {                                \
    int k_ = (K);                                                   \
    v2f p01 = {(A0), (A1)}, p23 = {(A2), (A3)};                     \
    _Pragma("unroll")                                               \
    for (int m = 0; m < MSEG; ++m) {                                \
      float fk = (k_ == m) ? 1.0f : 0.0f;                           \
      v2f fk2 = {fk, fk};                                           \
      acc01[m] = __builtin_elementwise_fma(fk2, p01, acc01[m]);     \
      acc23[m] = __builtin_elementwise_fma(fk2, p23, acc23[m]);     \
      cntk[m] += fk;                                                \
    } } while (0)

#define GRP1(KK, VA, VB, VC, VD) do {                \
    PIX1((KK).x, (VA).x, (VB).x, (VC).x, (VD).x);    \
    PIX1((KK).y, (VA).y, (VB).y, (VC).y, (VD).y);    \
    PIX1((KK).z, (VA).z, (VB).z, (VC).z, (VD).z);    \
    PIX1((KK).w, (VA).w, (VB).w, (VC).w, (VD).w);    \
  } while (0)

  const int base = blk*256 + tid;
  // software pipeline over 3 full iterations + 32-thread remainder
  int4 kc = kernv[base];
  float4 va = pc0[base], vb = pc1[base], vc = pc2[base], vd = pc3[base];

  {  // prefetch iter1, compute iter0
    const int p = base + STRIDE;
    int4 kn = kernv[p];
    float4 an = pc0[p], bn = pc1[p], cn = pc2[p], dn = pc3[p];
    GRP1(kc, va, vb, vc, vd);
    kc = kn; va = an; vb = bn; vc = cn; vd = dn;
  }
  {  // prefetch iter2, compute iter1
    const int p = base + 2*STRIDE;
    int4 kn = kernv[p];
    float4 an = pc0[p], bn = pc1[p], cn = pc2[p], dn = pc3[p];
    GRP1(kc, va, vb, vc, vd);
    kc = kn; va = an; vb = bn; vc = cn; vd = dn;
  }
  {  // prefetch remainder (tid<32), compute iter2, compute remainder
    int4 kr; float4 ar, br, cr, dr;
    const int pr = FULLCOV + blk*32 + (tid & 31);
    if (tid < 32) { kr = kernv[pr]; ar = pc0[pr]; br = pc1[pr]; cr = pc2[pr]; dr = pc3[pr]; }
    GRP1(kc, va, vb, vc, vd);
    if (tid < 32) GRP1(kr, ar, br, cr, dr);
  }
#undef GRP1
#undef PIX1

  // expand to flat view for the reduce-scatter (all static indices)
  float acc[80];
#pragma unroll
  for (int m = 0; m < MSEG; ++m) {
    acc[m]      = acc01[m].x;
    acc[16 + m] = acc01[m].y;
    acc[32 + m] = acc23[m].x;
    acc[48 + m] = acc23[m].y;
    acc[64 + m] = cntk[m];
  }

  // 64-value xor reduce-scatter: lane l ends holding the 64-lane sum of acc[l]
#pragma unroll
  for (int s = 0; s < 6; ++s) {
    const int dist = 32 >> s;
    const bool hi = (lane & dist) != 0;
#pragma unroll
    for (int v = 0; v < (32 >> s); ++v) {
      float keep = hi ? acc[v + (32 >> s)] : acc[v];
      float send = hi ? acc[v] : acc[v + (32 >> s)];
      acc[v] = keep + __shfl_xor(send, dist);
    }
  }
  // 16-value reduce-scatter on cnt_k: 4-lane group g ends holding cnt_k[g]
  float cn16[16];
#pragma unroll
  for (int m = 0; m < MSEG; ++m) cn16[m] = acc[64 + m];
#pragma unroll
  for (int s = 0; s < 4; ++s) {
    const int dist = 32 >> s;
    const int half = 8 >> s;
    const bool hi = (lane & dist) != 0;
#pragma unroll
    for (int v = 0; v < half; ++v) {
      float keep = hi ? cn16[v + half] : cn16[v];
      float send = hi ? cn16[v] : cn16[v + half];
      cn16[v] = keep + __shfl_xor(send, dist);
    }
  }
  float ckt = cn16[0];
  ckt += __shfl_xor(ckt, 2);
  ckt += __shfl_xor(ckt, 1);

  __shared__ float s_v[4][64];
  __shared__ float s_c[4][16];
  s_v[w][lane] = acc[0];
  if ((lane & 3) == 0) s_c[w][lane >> 2] = ckt;
  __syncthreads();

  if (tid < 64) {
    atomicAdd(&ws[OFF_A1 + n*80 + tid],
              s_v[0][tid] + s_v[1][tid] + s_v[2][tid] + s_v[3][tid]);
  } else if (tid < 80) {
    int i = tid - 64;
    atomicAdd(&ws[OFF_A1 + n*80 + tid],
              s_c[0][i] + s_c[1][i] + s_c[2][i] + s_c[3][i]);
  }
}

// ------------- finalize G (trivial: 80 floats per batch) -------------
__global__ __launch_bounds__(128) void finalize_G_kernel(float* __restrict__ ws) {
  const int n = blockIdx.x;
  const int tid = threadIdx.x;
  __shared__ float raw[80];
  if (tid < 80) raw[tid] = ws[OFF_A1 + n*80 + tid];
  __syncthreads();
  if (tid < 64) {
    int ch = tid >> 4, m = tid & 15;
    ws[OFF_GC + n*80 + m*4 + ch] = raw[tid] / fmaxf(raw[64 + m], 1.0f);
  } else if (tid < 80) {
    ws[OFF_GC + n*80 + tid] = raw[tid];   // cnt_k
  }
}

// ---------------- pass 2: agg-loss sums + cnt_t by text ----------------
__global__ __launch_bounds__(256, 4) void pass2_kernel(
    const float* __restrict__ preds, const int* __restrict__ targets,
    float* __restrict__ ws) {
  const int n = blockIdx.y, blk = blockIdx.x;
  const int tid = threadIdx.x, lane = tid & 63, w = tid >> 6;

  const float4* __restrict__ pc0 = (const float4*)(preds + ((size_t)n*6 + 2)*PPIX);
  const float4* __restrict__ pc1 = (const float4*)(preds + ((size_t)n*6 + 3)*PPIX);
  const float4* __restrict__ pc2 = (const float4*)(preds + ((size_t)n*6 + 4)*PPIX);
  const float4* __restrict__ pc3 = (const float4*)(preds + ((size_t)n*6 + 5)*PPIX);
  const int4*  __restrict__ textv = (const int4*)(targets + (size_t)n*2*PPIX);

  __shared__ float4 s_G[MSEG];
  if (tid < MSEG) s_G[tid] = ((const float4*)(ws + OFF_GC + n*80))[tid];

  // packed (lsum, cnt_t) accumulators
  v2f lc[MSEG];
#pragma unroll
  for (int m = 0; m < MSEG; ++m) lc[m] = (v2f){0.f, 0.f};

  const int base = blk*256 + tid;
  int4 tc = textv[base];
  float4 va = pc0[base], vb = pc1[base], vc = pc2[base], vd = pc3[base];
  __syncthreads();

#define PIX2(T, A0, A1, A2, A3) do {                            \
    int t_ = (T);                                               \
    float4 gv = s_G[t_];                                        \
    float dx = (A0) - gv.x, dy = (A1) - gv.y;                   \
    float dz = (A2) - gv.z, dw = (A3) - gv.w;                   \
    float sq = fmaf(dx, dx, fmaf(dy, dy, fmaf(dz, dz, dw*dw))); \
    float dd = fmaxf(__fsqrt_rn(sq) - DELTA_AGG, 0.f);          \
    float l = __logf(fmaf(dd, dd, 1.f));                        \
    v2f l1 = {l, 1.0f};                                         \
    _Pragma("unroll")                                           \
    for (int m = 0; m < MSEG; ++m) {                            \
      float fk = (t_ == m) ? 1.0f : 0.0f;                       \
      v2f fk2 = {fk, fk};                                       \
      lc[m] = __builtin_elementwise_fma(fk2, l1, lc[m]);        \
    } } while (0)

#define GRP2(TT, VA, VB, VC, VD) do {                \
    PIX2((TT).x, (VA).x, (VB).x, (VC).x, (VD).x);    \
    PIX2((TT).y, (VA).y, (VB).y, (VC).y, (VD).y);    \
    PIX2((TT).z, (VA).z, (VB).z, (VC).z, (VD).z);    \
    PIX2((TT).w, (VA).w, (VB).w, (VC).w, (VD).w);    \
  } while (0)

  {
    const int p = base + STRIDE;
    int4 tn = textv[p];
    float4 an = pc0[p], bn = pc1[p], cn = pc2[p], dn = pc3[p];
    GRP2(tc, va, vb, vc, vd);
    tc = tn; va = an; vb = bn; vc = cn; vd = dn;
  }
  {
    const int p = base + 2*STRIDE;
    int4 tn = textv[p];
    float4 an = pc0[p], bn = pc1[p], cn = pc2[p], dn = pc3[p];
    GRP2(tc, va, vb, vc, vd);
    tc = tn; va = an; vb = bn; vc = cn; vd = dn;
  }
  {
    int4 tr; float4 ar, br, cr, dr;
    const int pr = FULLCOV + blk*32 + (tid & 31);
    if (tid < 32) { tr = textv[pr]; ar = pc0[pr]; br = pc1[pr]; cr = pc2[pr]; dr = pc3[pr]; }
    GRP2(tc, va, vb, vc, vd);
    if (tid < 32) GRP2(tr, ar, br, cr, dr);
  }
#undef GRP2
#undef PIX2

  float ls[MSEG], ct[MSEG];
#pragma unroll
  for (int m = 0; m < MSEG; ++m) { ls[m] = lc[m].x; ct[m] = lc[m].y; }

  // two 16-value reduce-scatters: 4-lane group g ends holding value g
  float t0, t1;
#pragma unroll
  for (int s = 0; s < 4; ++s) {
    const int dist = 32 >> s; const int half = 8 >> s;
    const bool hi = (lane & dist) != 0;
#pragma unroll
    for (int v = 0; v < half; ++v) {
      float keep = hi ? ls[v + half] : ls[v];
      float send = hi ? ls[v] : ls[v + half];
      ls[v] = keep + __shfl_xor(send, dist);
    }
  }
  t0 = ls[0]; t0 += __shfl_xor(t0, 2); t0 += __shfl_xor(t0, 1);
#pragma unroll
  for (int s = 0; s < 4; ++s) {
    const int dist = 32 >> s; const int half = 8 >> s;
    const bool hi = (lane & dist) != 0;
#pragma unroll
    for (int v = 0; v < half; ++v) {
      float keep = hi ? ct[v + half] : ct[v];
      float send = hi ? ct[v] : ct[v + half];
      ct[v] = keep + __shfl_xor(send, dist);
    }
  }
  t1 = ct[0]; t1 += __shfl_xor(t1, 2); t1 += __shfl_xor(t1, 1);

  __shared__ float s_l[4][16];
  __shared__ float s_t[4][16];
  if ((lane & 3) == 0) { s_l[w][lane >> 2] = t0; s_t[w][lane >> 2] = t1; }
  __syncthreads();

  if (tid < 16)
    atomicAdd(&ws[OFF_A2 + n*32 + tid],
              s_l[0][tid] + s_l[1][tid] + s_l[2][tid] + s_l[3][tid]);
  else if (tid < 32) {
    int i = tid - 16;
    atomicAdd(&ws[OFF_A2 + n*32 + tid],
              s_t[0][i] + s_t[1][i] + s_t[2][i] + s_t[3][i]);
  }
}

// ------------- finalize: agg + dis (one block/batch, trivial reads) -------------
__global__ __launch_bounds__(256) void finalize2_kernel(
    const float* __restrict__ ws, float* __restrict__ out) {
  const int n = blockIdx.x;
  const int tid = threadIdx.x;

  __shared__ float s2[32];        // 0..15 lsum, 16..31 cnt_t
  __shared__ float sG[MSEG][4];
  __shared__ float sck[MSEG];
  __shared__ int   sval[MSEG];
  __shared__ int   snv;
  __shared__ float red[256];
  __shared__ float agg_sum;

  if (tid < 32) {
    s2[tid] = ws[OFF_A2 + n*32 + tid];
  } else if (tid >= 32 && tid < 48) {
    sck[tid - 32] = ws[OFF_GC + n*80 + 64 + (tid - 32)];
  } else if (tid >= 64 && tid < 128) {
    int i = tid - 64;
    sG[i >> 2][i & 3] = ws[OFF_GC + n*80 + i];
  }
  __syncthreads();
  if (tid < MSEG)
    sval[tid] = (tid >= 1) && (sck[tid] > 0.f) && (s2[16 + tid] > 0.f);
  __syncthreads();
  if (tid == 0) { int nv = 0; for (int m = 0; m < MSEG; m++) nv += sval[m]; snv = nv; }

  // agg
  float av = 0.f;
  if (tid < MSEG && sval[tid]) av = s2[tid] / fmaxf(s2[16 + tid], 1.0f);
  red[tid] = av;
  __syncthreads();
  for (int s = 128; s > 0; s >>= 1) {
    if (tid < s) red[tid] += red[tid + s];
    __syncthreads();
  }
  if (tid == 0) agg_sum = red[0];
  __syncthreads();

  // dis pairwise over 16x16
  float lp = 0.f;
  {
    int i = tid >> 4, j = tid & 15;
    if (i != j && sval[i] && sval[j]) {
      float dx = sG[i][0] - sG[j][0];
      float dy = sG[i][1] - sG[j][1];
      float dz = sG[i][2] - sG[j][2];
      float dw = sG[i][3] - sG[j][3];
      float dist = sqrtf(dx*dx + dy*dy + dz*dz + dw*dw);
      float t = fmaxf(DELTA_DIS - dist, 0.f);
      lp = logf(t*t + 1.f);
    }
  }
  red[tid] = lp;
  __syncthreads();
  for (int s = 128; s > 0; s >>= 1) {
    if (tid < s) red[tid] += red[tid + s];
    __syncthreads();
  }
  if (tid == 0) {
    int nv = snv;
    out[n] = agg_sum / (float)(nv > 1 ? nv : 1);
    out[NB + n] = (nv > 1) ? 0.5f * red[0] / (float)(nv * (nv - 1)) : 0.f;
  }
}

extern "C" void kernel_launch(void* const* d_in, const int* in_sizes, int n_in,
                              void* d_out, int out_size, void* d_ws, size_t ws_size,
                              hipStream_t stream) {
  const float* preds   = (const float*)d_in[0];
  const int*   targets = (const int*)d_in[1];
  float* out = (float*)d_out;
  float* ws  = (float*)d_ws;

  hipMemsetAsync(d_ws, 0, WS_ZERO_FLOATS * sizeof(float), stream);

  dim3 grid(GRIDX, NB);
  pass1_kernel<<<grid, 256, 0, stream>>>(preds, targets, ws);
  finalize_G_kernel<<<NB, 128, 0, stream>>>(ws);
  pass2_kernel<<<grid, 256, 0, stream>>>(preds, targets, ws);
  finalize2_kernel<<<NB, 256, 0, stream>>>(ws, out);
}